// Round 2
// baseline (86.543 us; speedup 1.0000x reference)
//
#include <hip/hip_runtime.h>

// ContrastiveLoss on MI355X — symmetric-Gram version.
// Shapes fixed by reference setup_inputs(): K=8 groups, BS=256, F=512,
// N1=2048 rows per half, N=4096 total. 128-row tiles are class-uniform.
// Upper-triangle tiles only: neg tiles update rows AND cols; pos tiles
// (incl. diagonal) handled in a second pass with both orientations.

#define KGRP 8
#define FD   512
#define N1T  2048
#define NT   4096
#define TEMPW 0.02f

typedef __attribute__((ext_vector_type(8))) short short8;
typedef __attribute__((ext_vector_type(4))) float f32x4;
typedef unsigned short ushort_t;

// ---- helpers ---------------------------------------------------------------

// order-preserving float<->uint encoding for atomicMax on floats
__device__ __forceinline__ unsigned enc_ord(float f) {
  unsigned u = __float_as_uint(f);
  return (u & 0x80000000u) ? ~u : (u | 0x80000000u);
}
__device__ __forceinline__ float dec_ord(unsigned u) {
  unsigned b = (u & 0x80000000u) ? (u & 0x7fffffffu) : ~u;
  return __uint_as_float(b);
}

// f32 -> bf16 round-to-nearest-even (bit trick)
__device__ __forceinline__ ushort_t f2bf(float f) {
  unsigned u = __float_as_uint(f);
  u = (u + 0x7fffu + ((u >> 16) & 1u)) >> 16;
  return (ushort_t)u;
}

// async global->LDS, 16B per lane; lds dest must be wave-uniform base
__device__ __forceinline__ void gld16(const void* g, void* l) {
  __builtin_amdgcn_global_load_lds(
      (const __attribute__((address_space(1))) unsigned*)g,
      (__attribute__((address_space(3))) unsigned*)l, 16, 0, 0);
}

// ---- shared 128x128 Gram-tile MFMA body ------------------------------------
// acc[m][n][j] = dot(feats[brow + r], feats[bcol + c]) for the wave's 64x64
// sub-tile. C/D layout (m89): within a 16x16 fragment col=lane&15,
// row=(lane>>4)*4 + j.
__device__ __forceinline__ void gram_tile(
    const ushort_t* __restrict__ bf, int brow, int bcol,
    ushort_t* ldsA, ushort_t* ldsB, f32x4 acc[4][4])
{
  const int t    = threadIdx.x;
  const int lane = t & 63, wave = t >> 6;
  const int wrow = (wave >> 1) << 6;   // 0 or 64
  const int wcol = (wave & 1) << 6;    // 0 or 64
  const int fr   = lane & 15;
  const int fh   = lane >> 4;
  const int r_in = t >> 2;             // staging row within 64-row stage
  const int cb   = (t & 3) << 3;       // staging col (bf16 elems)
  const int ldsw = wave << 10;         // wave-uniform LDS byte offset

  char* lA = (char*)ldsA;
  char* lB = (char*)ldsB;

#pragma unroll
  for (int m = 0; m < 4; m++)
#pragma unroll
    for (int n = 0; n < 4; n++)
      acc[m][n] = (f32x4){0.f, 0.f, 0.f, 0.f};

  for (int kk = 0; kk < FD; kk += 32) {
    gld16(bf + (size_t)(brow +      r_in) * FD + kk + cb, lA        + ldsw);
    gld16(bf + (size_t)(brow + 64 + r_in) * FD + kk + cb, lA + 4096 + ldsw);
    gld16(bf + (size_t)(bcol +      r_in) * FD + kk + cb, lB        + ldsw);
    gld16(bf + (size_t)(bcol + 64 + r_in) * FD + kk + cb, lB + 4096 + ldsw);
    __syncthreads();

    short8 a[4], b[4];
#pragma unroll
    for (int m = 0; m < 4; m++)
      a[m] = *(const short8*)(lA + ((wrow + (m << 4) + fr) << 6) + (fh << 4));
#pragma unroll
    for (int n = 0; n < 4; n++)
      b[n] = *(const short8*)(lB + ((wcol + (n << 4) + fr) << 6) + (fh << 4));

#pragma unroll
    for (int m = 0; m < 4; m++)
#pragma unroll
      for (int n = 0; n < 4; n++)
        acc[m][n] = __builtin_amdgcn_mfma_f32_16x16x32_bf16(a[m], b[n], acc[m][n], 0, 0, 0);
    __syncthreads();
  }
}

// ---- kernels ---------------------------------------------------------------

// init accumulators + class table + compact upper-triangle tile lists
__global__ void init_k(float* __restrict__ neg_sum, unsigned* __restrict__ neg_max,
                       float* __restrict__ sumS, float* __restrict__ corr,
                       int* __restrict__ cls, int* __restrict__ cnts,
                       int* __restrict__ neg_list, int* __restrict__ pos_list,
                       const int* __restrict__ ov)
{
  int i = blockIdx.x * 256 + threadIdx.x;
  if (i < NT) { neg_sum[i] = 0.f; neg_max[i] = 0u; }  // 0u < enc(any float)
  if (blockIdx.x == 0 && threadIdx.x == 0) {
    sumS[0] = 0.f;
    corr[0] = 0.f;
    int c[16];
    int excl = 0;
    for (int g = 0; g < KGRP; g++) c[g] = g;
    for (int g = 0; g < KGRP; g++) {
      if (ov[g]) c[KGRP + g] = g;
      else       { c[KGRP + g] = KGRP + excl; excl++; }
    }
    for (int g = 0; g < 16; g++) cls[g] = c[g];
    int nn = 0, np = 0;
    for (int bi = 0; bi < 32; bi++)
      for (int bj = bi; bj < 32; bj++) {
        if (c[bi >> 1] == c[bj >> 1]) pos_list[np++] = (bi << 5) | bj;
        else                          neg_list[nn++] = (bi << 5) | bj;
      }
    cnts[0] = nn;  // <= 480
    cnts[1] = np;  // <= 80
  }
}

// f32 -> bf16 (concat feats1, feats2), 8 elems/thread
__global__ void conv_k(const float* __restrict__ f1, const float* __restrict__ f2,
                       ushort_t* __restrict__ out)
{
  int i = blockIdx.x * 256 + threadIdx.x;
  size_t base = (size_t)i * 8;
  const size_t half = (size_t)N1T * FD;
  const float* sp = (base < half) ? (f1 + base) : (f2 + (base - half));
  float4 u0 = ((const float4*)sp)[0];
  float4 u1 = ((const float4*)sp)[1];
  short8 o;
  o[0] = (short)f2bf(u0.x); o[1] = (short)f2bf(u0.y);
  o[2] = (short)f2bf(u0.z); o[3] = (short)f2bf(u0.w);
  o[4] = (short)f2bf(u1.x); o[5] = (short)f2bf(u1.y);
  o[6] = (short)f2bf(u1.z); o[7] = (short)f2bf(u1.w);
  *(short8*)(out + base) = o;
}

// pass 1: upper-triangle negative tiles (bi<bj, different class).
// Row-side: neg_sum/neg_max for rows of bi. Col-side (symmetry): same for
// rows of bj via column reductions.
__global__ __launch_bounds__(256) void neg_pass(
    const ushort_t* __restrict__ bf, const int* __restrict__ cnts,
    const int* __restrict__ neg_list,
    float* __restrict__ neg_sum, unsigned* __restrict__ neg_max)
{
  if ((int)blockIdx.x >= cnts[0]) return;
  const int pr = neg_list[blockIdx.x];
  const int bi = pr >> 5, bj = pr & 31;

  __shared__ ushort_t ldsA[128 * 32], ldsB[128 * 32];
  f32x4 acc[4][4];
  gram_tile(bf, bi << 7, bj << 7, ldsA, ldsB, acc);

  const int t = threadIdx.x, lane = t & 63, wave = t >> 6;
  const int wrow = (wave >> 1) << 6, wcol = (wave & 1) << 6;
  const int fr = lane & 15, fh = lane >> 4;
  const int rbase = (bi << 7) + wrow + (fh << 2);
  const int cbase = (bj << 7) + wcol + fr;

  // row-side: per row r, sum/max over this tile's 64 cols held by 16 fr-lanes
#pragma unroll
  for (int m = 0; m < 4; m++) {
#pragma unroll
    for (int j = 0; j < 4; j++) {
      float s = 0.f, mx = -3.0e38f;
#pragma unroll
      for (int n = 0; n < 4; n++) {
        float d = acc[m][n][j];
        s += __expf(d * TEMPW);
        mx = fmaxf(mx, d);
      }
#pragma unroll
      for (int o = 1; o < 16; o <<= 1) {
        s  += __shfl_xor(s, o, 64);
        mx  = fmaxf(mx, __shfl_xor(mx, o, 64));
      }
      if (fr == 0) {
        int r = rbase + (m << 4) + j;
        atomicAdd(&neg_sum[r], s);
        atomicMax(&neg_max[r], enc_ord(mx));
      }
    }
  }

  // col-side: per col c, sum/max over this tile's 64 rows (16 per lane,
  // 4 fh lane-groups). Lane holds 4 cols (n=0..3).
#pragma unroll
  for (int n = 0; n < 4; n++) {
    float s = 0.f, mx = -3.0e38f;
#pragma unroll
    for (int m = 0; m < 4; m++)
#pragma unroll
      for (int j = 0; j < 4; j++) {
        float d = acc[m][n][j];
        s += __expf(d * TEMPW);
        mx = fmaxf(mx, d);
      }
    s += __shfl_xor(s, 16, 64); mx = fmaxf(mx, __shfl_xor(mx, 16, 64));
    s += __shfl_xor(s, 32, 64); mx = fmaxf(mx, __shfl_xor(mx, 32, 64));
    if (fh == 0) {
      int c = cbase + (n << 4);
      atomicAdd(&neg_sum[c], s);
      atomicMax(&neg_max[c], enc_ord(mx));
    }
  }
}

// pass 2: upper-triangle positive tiles (bi<=bj, same class), incl. all
// diagonal tiles. sumS += cw * (2x off-diag) * dots; correct counts both
// orientations for off-diag tiles.
__global__ __launch_bounds__(256) void pos_pass(
    const ushort_t* __restrict__ bf, const int* __restrict__ cnts,
    const int* __restrict__ pos_list, const unsigned* __restrict__ neg_max,
    float* __restrict__ sumS, float* __restrict__ corr)
{
  if ((int)blockIdx.x >= cnts[1]) return;
  const int pr = pos_list[blockIdx.x];
  const int bi = pr >> 5, bj = pr & 31;

  __shared__ ushort_t ldsA[128 * 32], ldsB[128 * 32];
  __shared__ float wsum[4];
  __shared__ int   wcnt[4];
  f32x4 acc[4][4];
  gram_tile(bf, bi << 7, bj << 7, ldsA, ldsB, acc);

  const int t = threadIdx.x, lane = t & 63, wave = t >> 6;
  const int wrow = (wave >> 1) << 6, wcol = (wave & 1) << 6;
  const int fr = lane & 15, fh = lane >> 4;
  const int rbase = (bi << 7) + wrow + (fh << 2);
  const int cbase = (bj << 7) + wcol + fr;
  const float cw = ((bi < 16) == (bj < 16)) ? 1.0f : 0.5f;

  float ssum = 0.f;
  int cc = 0;
  if (bi == bj) {
#pragma unroll
    for (int m = 0; m < 4; m++) {
#pragma unroll
      for (int j = 0; j < 4; j++) {
        int r = rbase + (m << 4) + j;
        float nmr = dec_ord(neg_max[r]);
#pragma unroll
        for (int n = 0; n < 4; n++) {
          int c = cbase + (n << 4);
          float d = acc[m][n][j];
          if (r != c) {  // exclude diagonal
            ssum += d;
            cc += (d > nmr) ? 1 : 0;
          }
        }
      }
    }
  } else {
    float nmc[4];
#pragma unroll
    for (int n = 0; n < 4; n++) nmc[n] = dec_ord(neg_max[cbase + (n << 4)]);
#pragma unroll
    for (int m = 0; m < 4; m++) {
#pragma unroll
      for (int j = 0; j < 4; j++) {
        int r = rbase + (m << 4) + j;
        float nmr = dec_ord(neg_max[r]);
#pragma unroll
        for (int n = 0; n < 4; n++) {
          float d = acc[m][n][j];
          ssum += d;                        // doubled after reduce
          cc += ((d > nmr) ? 1 : 0) + ((d > nmc[n]) ? 1 : 0);
        }
      }
    }
    ssum *= 2.0f;
  }

  // block-wide reduction -> one atomic pair per block
#pragma unroll
  for (int o = 1; o < 64; o <<= 1) {
    ssum += __shfl_xor(ssum, o, 64);
    cc   += __shfl_xor(cc, o, 64);
  }
  if (lane == 0) { wsum[wave] = ssum; wcnt[wave] = cc; }
  __syncthreads();
  if (t == 0) {
    float S2 = 0.f; int C2 = 0;
    for (int w = 0; w < 4; w++) { S2 += wsum[w]; C2 += wcnt[w]; }
    atomicAdd(sumS, cw * S2);
    atomicAdd(corr, (float)C2);
  }
}

// finalize: loss = (sum_i W_i*log(neg_sum_i) - TEMP*S) / total_pos; acc = C/total_pos
__global__ void fin_k(const float* __restrict__ neg_sum, const float* __restrict__ sumS,
                      const float* __restrict__ corr, const int* __restrict__ ov,
                      float* __restrict__ out)
{
  __shared__ double red[256];
  int t = threadIdx.x;
  double a = 0.0;
  for (int r = t; r < NT; r += 256) {
    int g = r >> 8;  // 256-row group, 0..15
    double W = 255.0 + 128.0 * (ov[g & 7] ? 1.0 : 0.0);
    a += W * log((double)neg_sum[r]);
  }
  red[t] = a;
  __syncthreads();
  if (t == 0) {
    double sw = 0.0;
    for (int i = 0; i < 256; i++) sw += red[i];
    double tp = 0.0;
    for (int g = 0; g < 16; g++) tp += 256.0 * (255.0 + 256.0 * (ov[g & 7] ? 1.0 : 0.0));
    double loss = (sw - (double)TEMPW * (double)sumS[0]) / tp;
    out[0] = (float)((double)corr[0] / tp);
    out[1] = (float)loss;
  }
}

// ---- launch ----------------------------------------------------------------

extern "C" void kernel_launch(void* const* d_in, const int* in_sizes, int n_in,
                              void* d_out, int out_size, void* d_ws, size_t ws_size,
                              hipStream_t stream)
{
  const float* f1 = (const float*)d_in[0];
  const float* f2 = (const float*)d_in[1];
  const int*   ov = (const int*)d_in[2];

  char* ws = (char*)d_ws;
  ushort_t* bf       = (ushort_t*)ws;                                    // 4 MB
  float*    neg_sum  = (float*)(ws + (size_t)(4 << 20));                 // 16 KB
  unsigned* neg_max  = (unsigned*)(ws + (size_t)(4 << 20) + (16 << 10)); // 16 KB
  float*    sumS     = (float*)(ws + (size_t)(4 << 20) + (32 << 10));
  float*    corr     = sumS + 1;
  int*      cnts     = (int*)(sumS + 2);            // 2 ints
  int*      cls      = cnts + 2;                    // 16 ints
  int*      neg_list = (int*)(ws + (size_t)(4 << 20) + (36 << 10));      // <=480 ints
  int*      pos_list = (int*)(ws + (size_t)(4 << 20) + (40 << 10));      // <=80 ints
  float*    out      = (float*)d_out;

  hipLaunchKernelGGL(init_k, dim3(16), dim3(256), 0, stream,
                     neg_sum, neg_max, sumS, corr, cls, cnts, neg_list, pos_list, ov);
  hipLaunchKernelGGL(conv_k, dim3(1024), dim3(256), 0, stream, f1, f2, bf);
  hipLaunchKernelGGL(neg_pass, dim3(480), dim3(256), 0, stream,
                     bf, cnts, neg_list, neg_sum, neg_max);
  hipLaunchKernelGGL(pos_pass, dim3(80), dim3(256), 0, stream,
                     bf, cnts, pos_list, neg_max, sumS, corr);
  hipLaunchKernelGGL(fin_k, dim3(1), dim3(256), 0, stream,
                     neg_sum, sumS, corr, ov, out);
}

// Round 3
// 51.721 us; speedup vs baseline: 1.6733x; 1.6733x over previous
//
#include <hip/hip_runtime.h>

// ContrastiveLoss on MI355X — symmetric Gram, fused tile pass, 3-deep
// counted-vmcnt LDS pipeline.
// Shapes fixed by reference setup_inputs(): K=8 groups, BS=256, F=512,
// N1=2048 rows per half, N=4096 total. 128-row tiles are class-uniform.
// Upper triangle only (528 tiles): neg tiles accumulate row+col exp-sums and
// maxes; pos tiles dump dots to scratch, compared after neg_max is final.

#define KGRP 8
#define FD   512
#define N1T  2048
#define NT   4096
#define TEMPW 0.02f

typedef __attribute__((ext_vector_type(8))) short short8;
typedef __attribute__((ext_vector_type(4))) float f32x4;
typedef unsigned short ushort_t;

// ---- helpers ---------------------------------------------------------------

// order-preserving float<->uint encoding for atomicMax on floats
__device__ __forceinline__ unsigned enc_ord(float f) {
  unsigned u = __float_as_uint(f);
  return (u & 0x80000000u) ? ~u : (u | 0x80000000u);
}
__device__ __forceinline__ float dec_ord(unsigned u) {
  unsigned b = (u & 0x80000000u) ? (u & 0x7fffffffu) : ~u;
  return __uint_as_float(b);
}

// f32 -> bf16 round-to-nearest-even (bit trick)
__device__ __forceinline__ ushort_t f2bf(float f) {
  unsigned u = __float_as_uint(f);
  u = (u + 0x7fffu + ((u >> 16) & 1u)) >> 16;
  return (ushort_t)u;
}

// async global->LDS, 16B per lane; lds dest is wave-uniform base + lane*16
__device__ __forceinline__ void gld16(const void* g, void* l) {
  __builtin_amdgcn_global_load_lds(
      (const __attribute__((address_space(1))) unsigned*)g,
      (__attribute__((address_space(3))) unsigned*)l, 16, 0, 0);
}

// ---- prep: bf16 convert + zero accumulators + class table + tile lists -----
__global__ __launch_bounds__(256) void prep_k(
    const float* __restrict__ f1, const float* __restrict__ f2,
    ushort_t* __restrict__ bf,
    float* __restrict__ neg_sum, unsigned* __restrict__ neg_max,
    float* __restrict__ sumS, float* __restrict__ corr,
    int* __restrict__ cnts, int* __restrict__ neg_list,
    int* __restrict__ pos_list, const int* __restrict__ ov)
{
  const int b = blockIdx.x, t = threadIdx.x;

  // f32 -> bf16 (concat feats1, feats2), 8 elems/thread
  {
    int i = b * 256 + t;
    size_t base = (size_t)i * 8;
    const size_t half = (size_t)N1T * FD;
    const float* sp = (base < half) ? (f1 + base) : (f2 + (base - half));
    float4 u0 = ((const float4*)sp)[0];
    float4 u1 = ((const float4*)sp)[1];
    short8 o;
    o[0] = (short)f2bf(u0.x); o[1] = (short)f2bf(u0.y);
    o[2] = (short)f2bf(u0.z); o[3] = (short)f2bf(u0.w);
    o[4] = (short)f2bf(u1.x); o[5] = (short)f2bf(u1.y);
    o[6] = (short)f2bf(u1.z); o[7] = (short)f2bf(u1.w);
    *(short8*)(bf + base) = o;
  }

  if (b >= 1 && b <= 16) {            // zero per-row accumulators
    int i = (b - 1) * 256 + t;
    neg_sum[i] = 0.f;
    neg_max[i] = 0u;                   // 0u < enc_ord(any float)
  }

  if (b == 0) {                        // parallel tile-list build
    __shared__ int c[16];
    if (t == 0) {
      sumS[0] = 0.f; corr[0] = 0.f; cnts[0] = 0; cnts[1] = 0;
      int excl = 0;
      for (int g = 0; g < KGRP; g++) c[g] = g;
      for (int g = 0; g < KGRP; g++) {
        if (ov[g]) c[KGRP + g] = g;
        else       { c[KGRP + g] = KGRP + excl; excl++; }
      }
    }
    __syncthreads();
    for (int p = t; p < 1024; p += 256) {
      int bi = p >> 5, bj = p & 31;
      if (bj < bi) continue;
      if (c[bi >> 1] == c[bj >> 1]) {
        int k = atomicAdd(&cnts[1], 1); pos_list[k] = (bi << 5) | bj;
      } else {
        int k = atomicAdd(&cnts[0], 1); neg_list[k] = (bi << 5) | bj;
      }
    }
  }
}

// ---- fused gram pass over all 528 upper-triangle tiles ---------------------
// 3-buffer LDS pipeline, 1 barrier + counted vmcnt per K-step.
__global__ __launch_bounds__(256) void gram_k(
    const ushort_t* __restrict__ bf, const int* __restrict__ cnts,
    const int* __restrict__ neg_list, const int* __restrict__ pos_list,
    float* __restrict__ neg_sum, unsigned* __restrict__ neg_max,
    float* __restrict__ pos_dots)
{
  __shared__ char lds[3 * 16384];      // 3 bufs x (A 8KB + B 8KB)

  const int nn = cnts[0];
  const int b  = blockIdx.x;
  const bool isneg = (b < nn);
  const int pr = isneg ? neg_list[b] : pos_list[b - nn];
  const int bi = pr >> 5, bj = pr & 31;
  const int brow = bi << 7, bcol = bj << 7;

  const int t    = threadIdx.x;
  const int lane = t & 63, wave = t >> 6;
  const int wrow = (wave >> 1) << 6, wcol = (wave & 1) << 6;
  const int fr   = lane & 15, fh = lane >> 4;
  const int r_in = t >> 2;             // staging row within 64-row half
  const int cb   = (t & 3) << 3;       // staging col (bf16 elems)
  const int ldsw = wave << 10;         // wave-uniform LDS byte offset

  const ushort_t* gA = bf + (size_t)(brow + r_in) * FD + cb;
  const ushort_t* gB = bf + (size_t)(bcol + r_in) * FD + cb;

  f32x4 acc[4][4];
#pragma unroll
  for (int m = 0; m < 4; m++)
#pragma unroll
    for (int n = 0; n < 4; n++)
      acc[m][n] = (f32x4){0.f, 0.f, 0.f, 0.f};

  auto stage = [&](int buf, int ks) {
    char* dst = lds + buf * 16384 + ldsw;
    const ushort_t* a = gA + (ks << 5);
    const ushort_t* p = gB + (ks << 5);
    gld16(a,                   dst);
    gld16(a + (size_t)64 * FD, dst + 4096);
    gld16(p,                   dst + 8192);
    gld16(p + (size_t)64 * FD, dst + 12288);
  };

  stage(0, 0);
  stage(1, 1);
  int cur = 0;
  for (int kk = 0; kk < 16; kk++) {
    // current buffer's loads were issued 2 iters ago; 4 newest may fly on
    if (kk == 15) asm volatile("s_waitcnt vmcnt(0)" ::: "memory");
    else          asm volatile("s_waitcnt vmcnt(4)" ::: "memory");
    __builtin_amdgcn_s_barrier();
    asm volatile("" ::: "memory");     // fence: no mem op crosses the barrier

    char* lA = lds + cur * 16384;
    char* lB = lA + 8192;
    short8 a[4], bb[4];
#pragma unroll
    for (int m = 0; m < 4; m++)
      a[m] = *(const short8*)(lA + ((wrow + (m << 4) + fr) << 6) + (fh << 4));
#pragma unroll
    for (int n = 0; n < 4; n++)
      bb[n] = *(const short8*)(lB + ((wcol + (n << 4) + fr) << 6) + (fh << 4));
#pragma unroll
    for (int m = 0; m < 4; m++)
#pragma unroll
      for (int n = 0; n < 4; n++)
        acc[m][n] = __builtin_amdgcn_mfma_f32_16x16x32_bf16(a[m], bb[n], acc[m][n], 0, 0, 0);

    if (kk + 2 < 16) {
      int nxt = cur - 1; if (nxt < 0) nxt = 2;   // (cur+2)%3
      stage(nxt, kk + 2);                        // overwrites buf read @kk-1
    }
    cur = cur + 1; if (cur == 3) cur = 0;
  }

  const int rbase = brow + wrow + (fh << 2);
  const int cbase = bcol + wcol + fr;

  if (isneg) {
    // single-exp epilogue: row sums/maxes + column sums/maxes in one sweep
    float colS[4] = {0.f, 0.f, 0.f, 0.f};
    float colM[4] = {-3.0e38f, -3.0e38f, -3.0e38f, -3.0e38f};
#pragma unroll
    for (int m = 0; m < 4; m++) {
#pragma unroll
      for (int j = 0; j < 4; j++) {
        float s = 0.f, mx = -3.0e38f;
#pragma unroll
        for (int n = 0; n < 4; n++) {
          float d = acc[m][n][j];
          float e = __expf(d * TEMPW);
          s += e; mx = fmaxf(mx, d);
          colS[n] += e; colM[n] = fmaxf(colM[n], d);
        }
#pragma unroll
        for (int o = 1; o < 16; o <<= 1) {
          s  += __shfl_xor(s, o, 64);
          mx  = fmaxf(mx, __shfl_xor(mx, o, 64));
        }
        if (fr == 0) {
          int r = rbase + (m << 4) + j;
          atomicAdd(&neg_sum[r], s);
          atomicMax(&neg_max[r], enc_ord(mx));
        }
      }
    }
#pragma unroll
    for (int n = 0; n < 4; n++) {
      float s = colS[n], mx = colM[n];
      s += __shfl_xor(s, 16, 64); mx = fmaxf(mx, __shfl_xor(mx, 16, 64));
      s += __shfl_xor(s, 32, 64); mx = fmaxf(mx, __shfl_xor(mx, 32, 64));
      if (fh == 0) {
        int c = cbase + (n << 4);
        atomicAdd(&neg_sum[c], s);
        atomicMax(&neg_max[c], enc_ord(mx));
      }
    }
  } else {
    // pos tile: dump dots to scratch (compared after neg_max is final)
    float* basep = pos_dots + (size_t)(b - nn) * 16384;
#pragma unroll
    for (int m = 0; m < 4; m++)
#pragma unroll
      for (int n = 0; n < 4; n++)
        *(f32x4*)(basep + (((m << 2) + n) << 10) + (t << 2)) = acc[m][n];
  }
}

// ---- pos compare + sums: needs final neg_max -------------------------------
__global__ __launch_bounds__(256) void pos_cmp_k(
    const float* __restrict__ pos_dots, const int* __restrict__ cnts,
    const int* __restrict__ pos_list, const unsigned* __restrict__ neg_max,
    float* __restrict__ sumS, float* __restrict__ corr)
{
  const int p = blockIdx.x;
  if (p >= cnts[1]) return;
  const int pr = pos_list[p];
  const int bi = pr >> 5, bj = pr & 31;

  const int t = threadIdx.x, lane = t & 63, wave = t >> 6;
  const int wrow = (wave >> 1) << 6, wcol = (wave & 1) << 6;
  const int fr = lane & 15, fh = lane >> 4;
  const int rbase = (bi << 7) + wrow + (fh << 2);
  const int cbase = (bj << 7) + wcol + fr;
  const float cw = ((bi < 16) == (bj < 16)) ? 1.0f : 0.5f;
  const float* basep = pos_dots + (size_t)p * 16384;

  __shared__ float wsum[4];
  __shared__ int   wcnt[4];

  float ssum = 0.f;
  int cc = 0;
  if (bi == bj) {
#pragma unroll
    for (int m = 0; m < 4; m++)
#pragma unroll
      for (int n = 0; n < 4; n++) {
        f32x4 v = *(const f32x4*)(basep + (((m << 2) + n) << 10) + (t << 2));
        int c = cbase + (n << 4);
#pragma unroll
        for (int j = 0; j < 4; j++) {
          int r = rbase + (m << 4) + j;
          if (r != c) {
            float d = v[j];
            ssum += d;
            cc += (d > dec_ord(neg_max[r])) ? 1 : 0;
          }
        }
      }
  } else {
    float nmr[4][4], nmc[4];
#pragma unroll
    for (int m = 0; m < 4; m++)
#pragma unroll
      for (int j = 0; j < 4; j++) nmr[m][j] = dec_ord(neg_max[rbase + (m << 4) + j]);
#pragma unroll
    for (int n = 0; n < 4; n++) nmc[n] = dec_ord(neg_max[cbase + (n << 4)]);
#pragma unroll
    for (int m = 0; m < 4; m++)
#pragma unroll
      for (int n = 0; n < 4; n++) {
        f32x4 v = *(const f32x4*)(basep + (((m << 2) + n) << 10) + (t << 2));
#pragma unroll
        for (int j = 0; j < 4; j++) {
          float d = v[j];
          ssum += d;
          cc += ((d > nmr[m][j]) ? 1 : 0) + ((d > nmc[n]) ? 1 : 0);
        }
      }
    ssum *= 2.0f;   // both orientations
  }
  ssum *= cw;

#pragma unroll
  for (int o = 1; o < 64; o <<= 1) {
    ssum += __shfl_xor(ssum, o, 64);
    cc   += __shfl_xor(cc, o, 64);
  }
  if (lane == 0) { wsum[wave] = ssum; wcnt[wave] = cc; }
  __syncthreads();
  if (t == 0) {
    float S2 = 0.f; int C2 = 0;
    for (int w = 0; w < 4; w++) { S2 += wsum[w]; C2 += wcnt[w]; }
    atomicAdd(sumS, S2);
    atomicAdd(corr, (float)C2);
  }
}

// ---- finalize --------------------------------------------------------------
__global__ void fin_k(const float* __restrict__ neg_sum, const float* __restrict__ sumS,
                      const float* __restrict__ corr, const int* __restrict__ ov,
                      float* __restrict__ out)
{
  __shared__ double red[256];
  int t = threadIdx.x;
  double a = 0.0;
  for (int r = t; r < NT; r += 256) {
    int g = r >> 8;  // 256-row group, 0..15
    double W = 255.0 + 128.0 * (ov[g & 7] ? 1.0 : 0.0);
    a += W * log((double)neg_sum[r]);
  }
  red[t] = a;
  __syncthreads();
  if (t == 0) {
    double sw = 0.0;
    for (int i = 0; i < 256; i++) sw += red[i];
    double tp = 0.0;
    for (int g = 0; g < 16; g++) tp += 256.0 * (255.0 + 256.0 * (ov[g & 7] ? 1.0 : 0.0));
    double loss = (sw - (double)TEMPW * (double)sumS[0]) / tp;
    out[0] = (float)((double)corr[0] / tp);
    out[1] = (float)loss;
  }
}

// ---- launch ----------------------------------------------------------------

extern "C" void kernel_launch(void* const* d_in, const int* in_sizes, int n_in,
                              void* d_out, int out_size, void* d_ws, size_t ws_size,
                              hipStream_t stream)
{
  const float* f1 = (const float*)d_in[0];
  const float* f2 = (const float*)d_in[1];
  const int*   ov = (const int*)d_in[2];

  char* ws = (char*)d_ws;
  ushort_t* bf       = (ushort_t*)ws;                                    // 4 MB
  float*    neg_sum  = (float*)(ws + (size_t)(4 << 20));                 // 16 KB
  unsigned* neg_max  = (unsigned*)(ws + (size_t)(4 << 20) + (16 << 10)); // 16 KB
  float*    sumS     = (float*)(ws + (size_t)(4 << 20) + (32 << 10));
  float*    corr     = sumS + 1;
  int*      cnts     = (int*)(sumS + 2);                                 // 2 ints
  int*      neg_list = (int*)(ws + (size_t)(4 << 20) + (36 << 10));      // <=480
  int*      pos_list = (int*)(ws + (size_t)(4 << 20) + (40 << 10));      // <=80
  float*    pos_dots = (float*)(ws + (size_t)(4 << 20) + (64 << 10));    // 5.25 MB
  float*    out      = (float*)d_out;

  hipLaunchKernelGGL(prep_k, dim3(1024), dim3(256), 0, stream,
                     f1, f2, bf, neg_sum, neg_max, sumS, corr, cnts,
                     neg_list, pos_list, ov);
  hipLaunchKernelGGL(gram_k, dim3(528), dim3(256), 0, stream,
                     bf, cnts, neg_list, pos_list, neg_sum, neg_max, pos_dots);
  hipLaunchKernelGGL(pos_cmp_k, dim3(80), dim3(256), 0, stream,
                     pos_dots, cnts, pos_list, neg_max, sumS, corr);
  hipLaunchKernelGGL(fin_k, dim3(1), dim3(256), 0, stream,
                     neg_sum, sumS, corr, ov, out);
}